// Round 11
// baseline (200.948 us; speedup 1.0000x reference)
//
#include <hip/hip_runtime.h>
#include <hip/hip_bf16.h>

// Problem constants
#define S_LEN   4096
#define D_MOD   512
#define BATCH   4
#define HALF_W  128
#define M_TOT   (BATCH * S_LEN)   // 16384

typedef __attribute__((ext_vector_type(8))) short bf16x8;
typedef __attribute__((ext_vector_type(4))) float f32x4;

__device__ __forceinline__ unsigned short f2bf(float f) {
    // round-to-nearest-even bf16 (values are finite here)
    unsigned int u = __float_as_uint(f);
    unsigned int r = (u + 0x7fffu + ((u >> 16) & 1u)) >> 16;
    return (unsigned short)r;
}

__device__ __forceinline__ void async_copy16(const void* g, void* l) {
    __builtin_amdgcn_global_load_lds(
        (const __attribute__((address_space(1))) void*)g,
        (__attribute__((address_space(3))) void*)l, 16, 0, 0);
}

// ---------------------------------------------------------------------------
// Kernel 1: fused converts (r10-passing, byte-identical).
__global__ __launch_bounds__(256) void convert_xw(const float* __restrict__ x,
                                                  const float* __restrict__ Wq,
                                                  const float* __restrict__ Wk,
                                                  const float* __restrict__ Wv,
                                                  unsigned short* __restrict__ xb,
                                                  unsigned short* __restrict__ Wt) {
    __shared__ float sT[64][65];
    const int t = threadIdx.x;
    const int bid = blockIdx.x;
    if (bid < 8192) {
        int i = (bid * 256 + t) * 4;
        float4 v = *(const float4*)(x + i);
        ushort4 o;
        o.x = f2bf(v.x); o.y = f2bf(v.y); o.z = f2bf(v.z); o.w = f2bf(v.w);
        *(ushort4*)(xb + i) = o;
        return;
    }
    const int j = bid - 8192;            // 0..191
    const int w = j >> 6;                // weight select (64 tiles each)
    const int rj = j & 63;
    const float* W = (w == 0) ? Wq : ((w == 1) ? Wk : Wv);
    const int n0 = (rj & 7) * 64, k0 = (rj >> 3) * 64;
    const int r = t >> 4, c4 = (t & 15) * 4;
    #pragma unroll
    for (int i = 0; i < 4; ++i) {
        float4 v = *(const float4*)(W + (size_t)(k0 + r + i * 16) * 512 + n0 + c4);
        sT[c4 + 0][r + i * 16] = v.x;
        sT[c4 + 1][r + i * 16] = v.y;
        sT[c4 + 2][r + i * 16] = v.z;
        sT[c4 + 3][r + i * 16] = v.w;
    }
    __syncthreads();
    #pragma unroll
    for (int i = 0; i < 4; ++i) {
        int rr = (t >> 4) + i * 16;   // n-local
        ushort4 o;
        o.x = f2bf(sT[rr][c4 + 0]);
        o.y = f2bf(sT[rr][c4 + 1]);
        o.z = f2bf(sT[rr][c4 + 2]);
        o.w = f2bf(sT[rr][c4 + 3]);
        *(ushort4*)(Wt + (size_t)w * 262144 + (size_t)(n0 + rr) * 512 + k0 + c4) = o;
    }
}

// ---------------------------------------------------------------------------
// Kernel 2: fused QKV GEMM (r10-passing, byte-identical: XCD swizzle +
// source-chunk-permute conflict-free LDS).
__global__ __launch_bounds__(256) void qkv_gemm(
    const unsigned short* __restrict__ xb, const unsigned short* __restrict__ Wt,
    const float* __restrict__ bq, const float* __restrict__ bk, const float* __restrict__ bv,
    unsigned short* __restrict__ Qo, unsigned short* __restrict__ Ko,
    unsigned short* __restrict__ Vt) {
    __shared__ __align__(16) char gsmem[34816];
    unsigned short* sA = (unsigned short*)gsmem;            // [128][64], chunk-swizzled
    unsigned short* sB = (unsigned short*)(gsmem + 16384);  // [128][64], chunk-swizzled
    unsigned short* sT = (unsigned short*)gsmem;            // [128][136] epilogue

    const int t = threadIdx.x;
    const int p = blockIdx.x;
    const int l = (p & 7) * 192 + (p >> 3);
    const int mi = l / 12;
    const int rzn = l - mi * 12;
    const int wsel = rzn >> 2;
    const int ni = rzn & 3;
    const int m0 = mi * 128;
    const int n0 = ni * 128;
    const unsigned short* Wb = Wt + (size_t)wsel * 262144;

    const int w = t >> 6, lane = t & 63;
    const int wm = (w & 1) * 64, wn = (w >> 1) * 64;
    const int qd = lane >> 4, l16 = lane & 15;

    f32x4 acc[4][4] = {};

    for (int k0 = 0; k0 < 512; k0 += 64) {
        __syncthreads();
        #pragma unroll
        for (int i = 0; i < 4; ++i) {
            int c = i * 256 + t;
            int row = c >> 3, cc = c & 7;
            int g = cc ^ (row & 7);                       // source-chunk permute
            async_copy16(xb + (size_t)(m0 + row) * 512 + k0 + g * 8, sA + c * 8);
            async_copy16(Wb + (size_t)(n0 + row) * 512 + k0 + g * 8, sB + c * 8);
        }
        __syncthreads();
        #pragma unroll
        for (int ks = 0; ks < 2; ++ks) {
            bf16x8 af[4], bfr[4];
            #pragma unroll
            for (int i = 0; i < 4; ++i) {
                int row = wm + i * 16 + l16;
                int ch = (ks * 4 + qd) ^ (row & 7);
                af[i] = *(const bf16x8*)(sA + row * 64 + ch * 8);
            }
            #pragma unroll
            for (int j = 0; j < 4; ++j) {
                int row = wn + j * 16 + l16;
                int ch = (ks * 4 + qd) ^ (row & 7);
                bfr[j] = *(const bf16x8*)(sB + row * 64 + ch * 8);
            }
            #pragma unroll
            for (int i = 0; i < 4; ++i)
                #pragma unroll
                for (int j = 0; j < 4; ++j)
                    acc[i][j] = __builtin_amdgcn_mfma_f32_16x16x32_bf16(af[i], bfr[j], acc[i][j], 0, 0, 0);
        }
    }

    const float* bias = (wsel == 0) ? bq : ((wsel == 1) ? bk : bv);
    __syncthreads();   // done reading sA/sB; sT aliases them

    if (wsel < 2) {
        #pragma unroll
        for (int j = 0; j < 4; ++j) {
            int n = wn + j * 16 + l16;
            float bj = bias[n0 + n];
            #pragma unroll
            for (int i = 0; i < 4; ++i) {
                int mb = wm + i * 16 + qd * 4;
                #pragma unroll
                for (int r = 0; r < 4; ++r)
                    sT[(mb + r) * 136 + n] = f2bf(acc[i][j][r] + bj);
            }
        }
        __syncthreads();
        unsigned short* Og = (wsel == 0) ? Qo : Ko;
        #pragma unroll
        for (int i2 = 0; i2 < 4; ++i2)
            #pragma unroll
            for (int i3 = 0; i3 < 2; ++i3) {
                int m = i2 * 32 + (t >> 3);
                int ch = (t & 7) + i3 * 8;
                bf16x8 v = *(const bf16x8*)(sT + m * 136 + ch * 8);
                *(bf16x8*)(Og + (size_t)(m0 + m) * 512 + n0 + ch * 8) = v;
            }
    } else {
        #pragma unroll
        for (int j = 0; j < 4; ++j) {
            int n = wn + j * 16 + l16;
            float bj = bias[n0 + n];
            #pragma unroll
            for (int i = 0; i < 4; ++i) {
                int mb = wm + i * 16 + qd * 4;
                #pragma unroll
                for (int r = 0; r < 4; ++r)
                    sT[n * 136 + mb + r] = f2bf(acc[i][j][r] + bj);
            }
        }
        __syncthreads();
        #pragma unroll
        for (int i2 = 0; i2 < 4; ++i2)
            #pragma unroll
            for (int i3 = 0; i3 < 2; ++i3) {
                int n = i2 * 32 + (t >> 3);
                int ch = (t & 7) + i3 * 8;
                bf16x8 v = *(const bf16x8*)(sT + n * 136 + ch * 8);
                *(bf16x8*)(Vt + (size_t)(n0 + n) * M_TOT + m0 + ch * 8) = v;
            }
    }
}

// ---------------------------------------------------------------------------
// Kernel 3: banded attention — r9-passing compute with K/V fragments loaded
// DIRECTLY from global into VGPRs (fine-grained vmcnt interleave, AITER-style)
// instead of bulk LDS staging + vmcnt(0) drains. Index formulas are the
// r6-proven ones with sKV[...] replaced by the global address it was staged
// from. sQ/sP/lsum/masking/epilogue byte-identical. 2 barriers/kt (sP only).
__global__ __launch_bounds__(256) void attn(const unsigned short* __restrict__ Qg,
                                            const unsigned short* __restrict__ Kg,
                                            const unsigned short* __restrict__ Vt,
                                            float* __restrict__ out) {
    __shared__ __align__(16) unsigned short sQ[32 * 520];    // 33,280 B (padded)
    __shared__ __align__(16) unsigned short sP[32 * 40];     //  2,560 B (padded)
    __shared__ float lsum[32];

    const int t = threadIdx.x;
    // XCD swizzle: physical p -> logical l = (p&7)*64 + p/8
    const int p = blockIdx.x;
    const int l = (p & 7) * 64 + (p >> 3);
    const int q0 = (l & 127) * 32;       // query offset within batch
    const int b = l >> 7;
    const int bS = b * S_LEN;
    const int w = t >> 6, lane = t & 63;
    const int qd = lane >> 4, l16 = lane & 15;
    const int qh = (w >> 1) * 16, kh = (w & 1) * 16;

    if (t < 32) lsum[t] = 0.f;

    // stage Q tile once: [32][512] bf16, rows padded to 520
    #pragma unroll
    for (int i = 0; i < 8; ++i) {
        int c = i * 256 + t;
        int row = c >> 6, cc = c & 63;
        async_copy16(Qg + (bS + q0 + row) * 512 + cc * 8, sQ + row * 520 + cc * 8);
    }
    __syncthreads();   // sQ ready (also covers lsum init)

    f32x4 oacc[16] = {};   // [c4][qt][dt]

    for (int kt = 0; kt < 9; ++kt) {
        int key0 = q0 - HALF_W + kt * 32;
        if (key0 + 32 <= 0 || key0 >= S_LEN) continue;   // block-uniform skip

        // ---- scores: S[32q][32k] = Q . K^T over full D; K fragments direct
        // from global (row clamped per-lane; garbage masked via P=0 below)
        int rowg = key0 + kh + l16;
        rowg = (rowg < 0) ? 0 : ((rowg > S_LEN - 1) ? S_LEN - 1 : rowg);
        const unsigned short* krow = Kg + (size_t)(bS + rowg) * 512 + qd * 8;
        f32x4 sacc = {0.f, 0.f, 0.f, 0.f};
        #pragma unroll
        for (int c4 = 0; c4 < 4; ++c4) {
            #pragma unroll
            for (int kc = 0; kc < 4; ++kc) {
                bf16x8 aq = *(const bf16x8*)(sQ + (qh + l16) * 520 + c4 * 128 + kc * 32 + qd * 8);
                bf16x8 bk8 = *(const bf16x8*)(krow + c4 * 128 + kc * 32);
                sacc = __builtin_amdgcn_mfma_f32_16x16x32_bf16(aq, bk8, sacc, 0, 0, 0);
            }
        }

        // ---- mask + exp + write P + row sums (r6-verbatim)
        const float scale = 0.04419417382415922f;   // 1/sqrt(512)
        #pragma unroll
        for (int r = 0; r < 4; ++r) {
            int qi = q0 + qh + qd * 4 + r;
            int kj = key0 + kh + l16;
            bool valid = (kj >= 0) && (kj < S_LEN) && (kj >= qi - HALF_W) && (kj <= qi + HALF_W);
            float p2 = valid ? __expf(sacc[r] * scale) : 0.f;
            sP[(qh + qd * 4 + r) * 40 + kh + l16] = f2bf(p2);
            float s = p2;
            s += __shfl_xor(s, 1);
            s += __shfl_xor(s, 2);
            s += __shfl_xor(s, 4);
            s += __shfl_xor(s, 8);
            if (l16 == 0) atomicAdd(&lsum[qh + qd * 4 + r], s);
        }

        __syncthreads();   // (A) sP published

        // ---- PV: O[32q][512d] += P . V; V fragments direct from global.
        // Was: sKV[(c4*128 + w*32 + dt*16 + l16)*32 + qd*8], staged from
        // Vt[row*M_TOT + bS + koff], koff = clamp(key0 + qd*8).
        int kk = key0 + qd * 8;
        int koff = (kk >= 0 && kk + 8 <= S_LEN) ? kk : 0;   // clamped, masked via P=0
        const unsigned short* vbase = Vt + (size_t)bS + koff;
        #pragma unroll
        for (int c4 = 0; c4 < 4; ++c4) {
            #pragma unroll
            for (int qt = 0; qt < 2; ++qt) {
                bf16x8 ap = *(const bf16x8*)(sP + (qt * 16 + l16) * 40 + qd * 8);
                #pragma unroll
                for (int dt = 0; dt < 2; ++dt) {
                    int dv = c4 * 128 + w * 32 + dt * 16 + l16;
                    bf16x8 bv8 = *(const bf16x8*)(vbase + (size_t)dv * M_TOT);
                    oacc[c4 * 4 + qt * 2 + dt] =
                        __builtin_amdgcn_mfma_f32_16x16x32_bf16(ap, bv8, oacc[c4 * 4 + qt * 2 + dt], 0, 0, 0);
                }
            }
        }

        __syncthreads();   // (B) sP reads done before next kt overwrites
    }

    __syncthreads();   // lsum final
    #pragma unroll
    for (int c4 = 0; c4 < 4; ++c4)
        #pragma unroll
        for (int qt = 0; qt < 2; ++qt)
            #pragma unroll
            for (int dt = 0; dt < 2; ++dt) {
                int dv = c4 * 128 + w * 32 + dt * 16 + l16;
                #pragma unroll
                for (int r = 0; r < 4; ++r) {
                    int q = qt * 16 + qd * 4 + r;
                    out[(size_t)(bS + q0 + q) * 512 + dv] = oacc[c4 * 4 + qt * 2 + dt][r] / lsum[q];
                }
            }
}

// ---------------------------------------------------------------------------
extern "C" void kernel_launch(void* const* d_in, const int* in_sizes, int n_in,
                              void* d_out, int out_size, void* d_ws, size_t ws_size,
                              hipStream_t stream) {
    const float* x  = (const float*)d_in[0];
    const float* Wq = (const float*)d_in[1];
    const float* bq = (const float*)d_in[2];
    const float* Wk = (const float*)d_in[3];
    const float* bk = (const float*)d_in[4];
    const float* Wv = (const float*)d_in[5];
    const float* bv = (const float*)d_in[6];
    float* out = (float*)d_out;

    char* ws = (char*)d_ws;
    unsigned short* xb = (unsigned short*)(ws);                    // 16 MB
    unsigned short* Wt = (unsigned short*)(ws + 16777216);         // 1.5 MB
    unsigned short* Qb = (unsigned short*)(ws + 18350080);         // 16 MB
    unsigned short* Kb = (unsigned short*)(ws + 35127296);         // 16 MB
    unsigned short* Vt = (unsigned short*)(ws + 51904512);         // 16 MB, [512][16384]

    convert_xw<<<8384, 256, 0, stream>>>(x, Wq, Wk, Wv, xb, Wt);
    qkv_gemm<<<1536, 256, 0, stream>>>(xb, Wt, bq, bk, bv, Qb, Kb, Vt);
    attn<<<512, 256, 0, stream>>>(Qb, Kb, Vt, out);
}

// Round 12
// 174.329 us; speedup vs baseline: 1.1527x; 1.1527x over previous
//
#include <hip/hip_runtime.h>
#include <hip/hip_bf16.h>

// Problem constants
#define S_LEN   4096
#define D_MOD   512
#define BATCH   4
#define HALF_W  128
#define M_TOT   (BATCH * S_LEN)   // 16384

typedef __attribute__((ext_vector_type(8))) short bf16x8;
typedef __attribute__((ext_vector_type(4))) float f32x4;

__device__ __forceinline__ unsigned short f2bf(float f) {
    // round-to-nearest-even bf16 (values are finite here)
    unsigned int u = __float_as_uint(f);
    unsigned int r = (u + 0x7fffu + ((u >> 16) & 1u)) >> 16;
    return (unsigned short)r;
}

__device__ __forceinline__ void async_copy16(const void* g, void* l) {
    __builtin_amdgcn_global_load_lds(
        (const __attribute__((address_space(1))) void*)g,
        (__attribute__((address_space(3))) void*)l, 16, 0, 0);
}

// ---------------------------------------------------------------------------
// Kernel 1: fused converts (r10-passing, byte-identical).
__global__ __launch_bounds__(256) void convert_xw(const float* __restrict__ x,
                                                  const float* __restrict__ Wq,
                                                  const float* __restrict__ Wk,
                                                  const float* __restrict__ Wv,
                                                  unsigned short* __restrict__ xb,
                                                  unsigned short* __restrict__ Wt) {
    __shared__ float sT[64][65];
    const int t = threadIdx.x;
    const int bid = blockIdx.x;
    if (bid < 8192) {
        int i = (bid * 256 + t) * 4;
        float4 v = *(const float4*)(x + i);
        ushort4 o;
        o.x = f2bf(v.x); o.y = f2bf(v.y); o.z = f2bf(v.z); o.w = f2bf(v.w);
        *(ushort4*)(xb + i) = o;
        return;
    }
    const int j = bid - 8192;            // 0..191
    const int w = j >> 6;                // weight select (64 tiles each)
    const int rj = j & 63;
    const float* W = (w == 0) ? Wq : ((w == 1) ? Wk : Wv);
    const int n0 = (rj & 7) * 64, k0 = (rj >> 3) * 64;
    const int r = t >> 4, c4 = (t & 15) * 4;
    #pragma unroll
    for (int i = 0; i < 4; ++i) {
        float4 v = *(const float4*)(W + (size_t)(k0 + r + i * 16) * 512 + n0 + c4);
        sT[c4 + 0][r + i * 16] = v.x;
        sT[c4 + 1][r + i * 16] = v.y;
        sT[c4 + 2][r + i * 16] = v.z;
        sT[c4 + 3][r + i * 16] = v.w;
    }
    __syncthreads();
    #pragma unroll
    for (int i = 0; i < 4; ++i) {
        int rr = (t >> 4) + i * 16;   // n-local
        ushort4 o;
        o.x = f2bf(sT[rr][c4 + 0]);
        o.y = f2bf(sT[rr][c4 + 1]);
        o.z = f2bf(sT[rr][c4 + 2]);
        o.w = f2bf(sT[rr][c4 + 3]);
        *(ushort4*)(Wt + (size_t)w * 262144 + (size_t)(n0 + rr) * 512 + k0 + c4) = o;
    }
}

// ---------------------------------------------------------------------------
// Kernel 2: fused QKV GEMM (r10-passing, byte-identical: XCD swizzle +
// source-chunk-permute conflict-free LDS).
__global__ __launch_bounds__(256) void qkv_gemm(
    const unsigned short* __restrict__ xb, const unsigned short* __restrict__ Wt,
    const float* __restrict__ bq, const float* __restrict__ bk, const float* __restrict__ bv,
    unsigned short* __restrict__ Qo, unsigned short* __restrict__ Ko,
    unsigned short* __restrict__ Vt) {
    __shared__ __align__(16) char gsmem[34816];
    unsigned short* sA = (unsigned short*)gsmem;            // [128][64], chunk-swizzled
    unsigned short* sB = (unsigned short*)(gsmem + 16384);  // [128][64], chunk-swizzled
    unsigned short* sT = (unsigned short*)gsmem;            // [128][136] epilogue

    const int t = threadIdx.x;
    const int p = blockIdx.x;
    const int l = (p & 7) * 192 + (p >> 3);
    const int mi = l / 12;
    const int rzn = l - mi * 12;
    const int wsel = rzn >> 2;
    const int ni = rzn & 3;
    const int m0 = mi * 128;
    const int n0 = ni * 128;
    const unsigned short* Wb = Wt + (size_t)wsel * 262144;

    const int w = t >> 6, lane = t & 63;
    const int wm = (w & 1) * 64, wn = (w >> 1) * 64;
    const int qd = lane >> 4, l16 = lane & 15;

    f32x4 acc[4][4] = {};

    for (int k0 = 0; k0 < 512; k0 += 64) {
        __syncthreads();
        #pragma unroll
        for (int i = 0; i < 4; ++i) {
            int c = i * 256 + t;
            int row = c >> 3, cc = c & 7;
            int g = cc ^ (row & 7);                       // source-chunk permute
            async_copy16(xb + (size_t)(m0 + row) * 512 + k0 + g * 8, sA + c * 8);
            async_copy16(Wb + (size_t)(n0 + row) * 512 + k0 + g * 8, sB + c * 8);
        }
        __syncthreads();
        #pragma unroll
        for (int ks = 0; ks < 2; ++ks) {
            bf16x8 af[4], bfr[4];
            #pragma unroll
            for (int i = 0; i < 4; ++i) {
                int row = wm + i * 16 + l16;
                int ch = (ks * 4 + qd) ^ (row & 7);
                af[i] = *(const bf16x8*)(sA + row * 64 + ch * 8);
            }
            #pragma unroll
            for (int j = 0; j < 4; ++j) {
                int row = wn + j * 16 + l16;
                int ch = (ks * 4 + qd) ^ (row & 7);
                bfr[j] = *(const bf16x8*)(sB + row * 64 + ch * 8);
            }
            #pragma unroll
            for (int i = 0; i < 4; ++i)
                #pragma unroll
                for (int j = 0; j < 4; ++j)
                    acc[i][j] = __builtin_amdgcn_mfma_f32_16x16x32_bf16(af[i], bfr[j], acc[i][j], 0, 0, 0);
        }
    }

    const float* bias = (wsel == 0) ? bq : ((wsel == 1) ? bk : bv);
    __syncthreads();   // done reading sA/sB; sT aliases them

    if (wsel < 2) {
        #pragma unroll
        for (int j = 0; j < 4; ++j) {
            int n = wn + j * 16 + l16;
            float bj = bias[n0 + n];
            #pragma unroll
            for (int i = 0; i < 4; ++i) {
                int mb = wm + i * 16 + qd * 4;
                #pragma unroll
                for (int r = 0; r < 4; ++r)
                    sT[(mb + r) * 136 + n] = f2bf(acc[i][j][r] + bj);
            }
        }
        __syncthreads();
        unsigned short* Og = (wsel == 0) ? Qo : Ko;
        #pragma unroll
        for (int i2 = 0; i2 < 4; ++i2)
            #pragma unroll
            for (int i3 = 0; i3 < 2; ++i3) {
                int m = i2 * 32 + (t >> 3);
                int ch = (t & 7) + i3 * 8;
                bf16x8 v = *(const bf16x8*)(sT + m * 136 + ch * 8);
                *(bf16x8*)(Og + (size_t)(m0 + m) * 512 + n0 + ch * 8) = v;
            }
    } else {
        #pragma unroll
        for (int j = 0; j < 4; ++j) {
            int n = wn + j * 16 + l16;
            float bj = bias[n0 + n];
            #pragma unroll
            for (int i = 0; i < 4; ++i) {
                int mb = wm + i * 16 + qd * 4;
                #pragma unroll
                for (int r = 0; r < 4; ++r)
                    sT[n * 136 + mb + r] = f2bf(acc[i][j][r] + bj);
            }
        }
        __syncthreads();
        #pragma unroll
        for (int i2 = 0; i2 < 4; ++i2)
            #pragma unroll
            for (int i3 = 0; i3 < 2; ++i3) {
                int n = i2 * 32 + (t >> 3);
                int ch = (t & 7) + i3 * 8;
                bf16x8 v = *(const bf16x8*)(sT + n * 136 + ch * 8);
                *(bf16x8*)(Vt + (size_t)(n0 + n) * M_TOT + m0 + ch * 8) = v;
            }
    }
}

// ---------------------------------------------------------------------------
// Kernel 3: banded attention — r10-passing compute with a 2-phase software
// pipeline: Q in registers (same lane->element map as the r10 sQ A-operand),
// separate sK/sV buffers, each stage issued a full compute phase before its
// consuming barrier (drain finds loads landed). Staging patterns, masks, sP,
// lsum, epilogue: r10-verbatim.
__global__ __launch_bounds__(256) void attn(const unsigned short* __restrict__ Qg,
                                            const unsigned short* __restrict__ Kg,
                                            const unsigned short* __restrict__ Vt,
                                            float* __restrict__ out) {
    __shared__ __align__(16) unsigned short sK[32 * 520];   // 33,280 B (padded)
    __shared__ __align__(16) unsigned short sV[512 * 32];   // 32,768 B
    __shared__ __align__(16) unsigned short sP[32 * 40];    //  2,560 B (padded)
    __shared__ float lsum[32];

    const int t = threadIdx.x;
    // XCD swizzle: physical p -> logical l = (p&7)*64 + p/8
    const int p = blockIdx.x;
    const int l = (p & 7) * 64 + (p >> 3);
    const int q0 = (l & 127) * 32;       // query offset within batch
    const int b = l >> 7;
    const int bS = b * S_LEN;
    const int w = t >> 6, lane = t & 63;
    const int qd = lane >> 4, l16 = lane & 15;
    const int qh = (w >> 1) * 16, kh = (w & 1) * 16;

    if (t < 32) lsum[t] = 0.f;

    // Q fragments in registers: qf[c4*4+kc] supplies the A-operand element
    // Q[q0+qh+l16][c4*128 + kc*32 + qd*8 + j] — identical map to r10's sQ read.
    bf16x8 qf[16];
    {
        const unsigned short* qrow = Qg + (size_t)(bS + q0 + qh + l16) * 512 + qd * 8;
        #pragma unroll
        for (int kc = 0; kc < 16; ++kc) qf[kc] = *(const bf16x8*)(qrow + kc * 32);
    }

    f32x4 oacc[16] = {};   // [c4][qt][dt]

    auto stageK = [&](int key0) {   // r10-verbatim pattern, target sK
        #pragma unroll
        for (int i = 0; i < 8; ++i) {
            int c = i * 256 + t;
            int row = c >> 6, cc = c & 63;
            int rowg = key0 + row;
            rowg = (rowg < 0) ? 0 : ((rowg > S_LEN - 1) ? S_LEN - 1 : rowg);
            async_copy16(Kg + (size_t)(bS + rowg) * 512 + cc * 8, sK + row * 520 + cc * 8);
        }
    };
    auto stageV = [&](int key0) {   // r10-verbatim pattern, target sV
        #pragma unroll
        for (int i = 0; i < 8; ++i) {
            int c = i * 256 + t;
            int row = c >> 2, cc = c & 3;
            int kk = key0 + cc * 8;
            int koff = (kk >= 0 && kk + 8 <= S_LEN) ? kk : 0;   // clamped, masked via P=0
            async_copy16(Vt + (size_t)row * M_TOT + bS + koff, sV + c * 8);
        }
    };

    // valid kt range (block-uniform): key0 = q0-128+32kt in (-32, S_LEN)
    const int ti = q0 >> 5;
    const int kt_lo = (4 - ti) > 0 ? (4 - ti) : 0;
    const int kh_t = (4192 - q0) >> 5;
    const int kt_hi = kh_t < 8 ? kh_t : 8;

    stageK(q0 - HALF_W + kt_lo * 32);   // prefetch first K tile

    for (int kt = kt_lo; kt <= kt_hi; ++kt) {
        int key0 = q0 - HALF_W + kt * 32;

        __syncthreads();                 // A: K(kt) landed; sV free (prev PV done)
        stageV(key0);                    // in flight across the scores phase

        // ---- scores: S[32q][32k] = Q . K^T over full D (A from registers)
        f32x4 sacc = {0.f, 0.f, 0.f, 0.f};
        #pragma unroll
        for (int c4 = 0; c4 < 4; ++c4) {
            #pragma unroll
            for (int kc = 0; kc < 4; ++kc) {
                bf16x8 bk8 = *(const bf16x8*)(sK + (kh + l16) * 520 + c4 * 128 + kc * 32 + qd * 8);
                sacc = __builtin_amdgcn_mfma_f32_16x16x32_bf16(qf[c4 * 4 + kc], bk8, sacc, 0, 0, 0);
            }
        }

        // ---- mask + exp + write P + row sums (r10-verbatim)
        const float scale = 0.04419417382415922f;   // 1/sqrt(512)
        #pragma unroll
        for (int r = 0; r < 4; ++r) {
            int qi = q0 + qh + qd * 4 + r;
            int kj = key0 + kh + l16;
            bool valid = (kj >= 0) && (kj < S_LEN) && (kj >= qi - HALF_W) && (kj <= qi + HALF_W);
            float p2 = valid ? __expf(sacc[r] * scale) : 0.f;
            sP[(qh + qd * 4 + r) * 40 + kh + l16] = f2bf(p2);
            float s = p2;
            s += __shfl_xor(s, 1);
            s += __shfl_xor(s, 2);
            s += __shfl_xor(s, 4);
            s += __shfl_xor(s, 8);
            if (l16 == 0) atomicAdd(&lsum[qh + qd * 4 + r], s);
        }

        __syncthreads();                 // B: V(kt) landed; sP published; sK reads done
        if (kt < kt_hi) stageK(key0 + 32);   // in flight across the PV phase

        // ---- PV: O[32q][512d] += P . V (r10-verbatim reads)
        #pragma unroll
        for (int c4 = 0; c4 < 4; ++c4) {
            #pragma unroll
            for (int qt = 0; qt < 2; ++qt) {
                bf16x8 ap = *(const bf16x8*)(sP + (qt * 16 + l16) * 40 + qd * 8);
                #pragma unroll
                for (int dt = 0; dt < 2; ++dt) {
                    bf16x8 bv8 = *(const bf16x8*)(sV + (c4 * 128 + w * 32 + dt * 16 + l16) * 32 + qd * 8);
                    oacc[c4 * 4 + qt * 2 + dt] =
                        __builtin_amdgcn_mfma_f32_16x16x32_bf16(ap, bv8, oacc[c4 * 4 + qt * 2 + dt], 0, 0, 0);
                }
            }
        }
    }

    // epilogue (r10-verbatim; lsum was published at the last barrier B)
    #pragma unroll
    for (int c4 = 0; c4 < 4; ++c4)
        #pragma unroll
        for (int qt = 0; qt < 2; ++qt)
            #pragma unroll
            for (int dt = 0; dt < 2; ++dt) {
                int dv = c4 * 128 + w * 32 + dt * 16 + l16;
                #pragma unroll
                for (int r = 0; r < 4; ++r) {
                    int q = qt * 16 + qd * 4 + r;
                    out[(size_t)(bS + q0 + q) * 512 + dv] = oacc[c4 * 4 + qt * 2 + dt][r] / lsum[q];
                }
            }
}

// ---------------------------------------------------------------------------
extern "C" void kernel_launch(void* const* d_in, const int* in_sizes, int n_in,
                              void* d_out, int out_size, void* d_ws, size_t ws_size,
                              hipStream_t stream) {
    const float* x  = (const float*)d_in[0];
    const float* Wq = (const float*)d_in[1];
    const float* bq = (const float*)d_in[2];
    const float* Wk = (const float*)d_in[3];
    const float* bk = (const float*)d_in[4];
    const float* Wv = (const float*)d_in[5];
    const float* bv = (const float*)d_in[6];
    float* out = (float*)d_out;

    char* ws = (char*)d_ws;
    unsigned short* xb = (unsigned short*)(ws);                    // 16 MB
    unsigned short* Wt = (unsigned short*)(ws + 16777216);         // 1.5 MB
    unsigned short* Qb = (unsigned short*)(ws + 18350080);         // 16 MB
    unsigned short* Kb = (unsigned short*)(ws + 35127296);         // 16 MB
    unsigned short* Vt = (unsigned short*)(ws + 51904512);         // 16 MB, [512][16384]

    convert_xw<<<8384, 256, 0, stream>>>(x, Wq, Wk, Wv, xb, Wt);
    qkv_gemm<<<1536, 256, 0, stream>>>(xb, Wt, bq, bk, bv, Qb, Kb, Vt);
    attn<<<512, 256, 0, stream>>>(Qb, Kb, Vt, out);
}